// Round 15
// baseline (596.723 us; speedup 1.0000x reference)
//
#include <hip/hip_runtime.h>

#define Bv 1024
#define Ev 256
#define Lv 8
#define Rv 10000
#define NP1 10001
#define PS2 10240      // padded row stride (multiple of 2048)
#define NPAD 10112     // fc2 rows padded to 79*128
#define BM 64
#define BN 128
#define NSLICE 16
#define NSLOT 158      // 79 N-tiles * 2 wave-halves
#define RPSTRIDE 160   // padded slot stride for rowPart
#define HLS 264        // padded LDS row stride (shorts) for h staging

typedef __attribute__((ext_vector_type(8))) short bf16x8;
typedef __attribute__((ext_vector_type(4))) float f32x4;

__device__ __forceinline__ float b2f(unsigned short u) {
    union { unsigned int i; float f; } v; v.i = ((unsigned int)u) << 16; return v.f;
}
__device__ __forceinline__ unsigned short f2b(float f) {
    union { float f; unsigned int i; } v; v.f = f;
    unsigned int r = v.i + 0x7fffu + ((v.i >> 16) & 1u);
    return (unsigned short)(r >> 16);
}
// fast tanh: (e-1)/(e+1), e=exp(2x); clamp keeps e finite (no inf/inf NaN)
__device__ __forceinline__ float ftanh(float x) {
    x = fminf(fmaxf(x, -30.f), 30.f);
    float e = __expf(2.f * x);
    return (e - 1.f) / (e + 1.f);
}
__device__ __forceinline__ void glds16(const void* g, void* l) {
    __builtin_amdgcn_global_load_lds(
        (const __attribute__((address_space(1))) void*)g,
        (__attribute__((address_space(3))) void*)l, 16, 0, 0);
}

// ---------- 64x128 tile GEMM, m97 schedule, BK=64 ----------
// mode&7: 0 f32 | 2 bf16 slice outB+bz*Bv*Ev | 3 bf16 zero-invalid | 5 exp+rowsums
// mode>>4 (XCD swizzle): 0 3-D grid | 1 fc2(1280, 1-D) | 2 emb1(512, 1-D, 16 slices)
__global__ __launch_bounds__(256) void gemm_tile(
    const unsigned short* __restrict__ A1, int lda1,
    const unsigned short* __restrict__ W1, int ldw1,
    const float* __restrict__ bias1,
    int Ktot, int kchunk, int Ncols, int mode,
    float* __restrict__ outF, unsigned short* __restrict__ outB, int ldc,
    float* __restrict__ rowPart, float* __restrict__ sfLastU)
{
    __shared__ unsigned short As[2][BM * 32];   // 2 x 4 KB
    __shared__ unsigned short Bs[2][BN * 32];   // 2 x 8 KB

    int bmode = mode & 7;
    int swz   = mode >> 4;
    int bx, by, bz;
    if (swz == 1) {            // fc2: same-N tiles share bid%8 -> same XCD
        int r = blockIdx.x & 7, q = blockIdx.x >> 3;   // q 0..159
        bx = q & 15; by = r + (q >> 4) * 8; bz = 0;
        if (by >= NPAD / BN) return;
    } else if (swz == 2) {     // emb1: same-K-slice shares bid%8 (16 slices)
        int r = blockIdx.x & 7, q = blockIdx.x >> 3;   // q 0..63
        bz = r + (q >> 5) * 8; bx = (q & 31) >> 1; by = q & 1;
    } else {
        bx = blockIdx.x; by = blockIdx.y; bz = blockIdx.z;
    }

    int tid  = threadIdx.x;
    int wave = tid >> 6;
    int lane = tid & 63;
    int quad = lane >> 4;
    int l16  = lane & 15;
    int wm = (wave & 1) * 32;
    int wn = (wave >> 1) * 64;
    int m0 = bx * BM;
    int n0 = by * BN;
    int k0 = bz * kchunk;
    int k1 = k0 + kchunk; if (k1 > Ktot) k1 = Ktot;   // kchunk mult of 64 here

    f32x4 acc[2][4];
#pragma unroll
    for (int i = 0; i < 2; ++i)
#pragma unroll
        for (int j = 0; j < 4; ++j) acc[i][j] = (f32x4){0.f, 0.f, 0.f, 0.f};

    int c0 = tid, c1 = 256 + tid;
    int row0 = c0 >> 2, row1 = c1 >> 2;
    int g80 = ((c0 & 3) ^ (row0 & 3) ^ ((row0 >> 2) & 3)) * 8;
    int g81 = ((c1 & 3) ^ (row1 & 3) ^ ((row1 >> 2) & 3)) * 8;

    bool first = true;
    for (int k = k0; k < k1; k += 64) {
        if (!first) __syncthreads();
        first = false;
#pragma unroll
        for (int h = 0; h < 2; ++h) {
            int kk = k + h * 32;
            glds16(A1 + (size_t)(m0 + row0) * lda1 + kk + g80, As[h] + (wave * 64) * 8);
            glds16(W1 + (size_t)(n0 + row0) * ldw1 + kk + g80, Bs[h] + (wave * 64) * 8);
            glds16(W1 + (size_t)(n0 + row1) * ldw1 + kk + g81, Bs[h] + (256 + wave * 64) * 8);
        }
        asm volatile("s_waitcnt vmcnt(0)" ::: "memory");
        __syncthreads();

#pragma unroll
        for (int h = 0; h < 2; ++h) {
            bf16x8 af[2], bfr[4];
#pragma unroll
            for (int t = 0; t < 2; ++t) {
                int m = wm + t * 16 + l16;
                int ca = quad ^ (m & 3) ^ ((m >> 2) & 3);
                af[t] = *(const bf16x8*)(As[h] + m * 32 + ca * 8);
            }
#pragma unroll
            for (int t = 0; t < 4; ++t) {
                int n = wn + t * 16 + l16;
                int cb = quad ^ (n & 3) ^ ((n >> 2) & 3);
                bfr[t] = *(const bf16x8*)(Bs[h] + n * 32 + cb * 8);
            }
#pragma unroll
            for (int i = 0; i < 2; ++i)
#pragma unroll
                for (int j = 0; j < 4; ++j)
                    acc[i][j] = __builtin_amdgcn_mfma_f32_16x16x32_bf16(
                        af[i], bfr[j], acc[i][j], 0, 0, 0);
        }
    }

    // D mapping: col = lane&15, row = quad*4 + reg
    if (bmode == 5) {
        // exp epilogue: sfA <- bf16(exp(logit)) (pad cols zeroed),
        // rowPart[m][by*2+half] <- partial row sum, sfLastU[m] <- exp at col Rv
        float rsum[2][4];
#pragma unroll
        for (int i = 0; i < 2; ++i)
#pragma unroll
            for (int r = 0; r < 4; ++r) rsum[i][r] = 0.f;
#pragma unroll
        for (int j = 0; j < 4; ++j) {
            int n = n0 + wn + j * 16 + l16;
            bool valid = (n < Ncols);
            float bsum = valid ? bias1[n] : 0.f;
#pragma unroll
            for (int i = 0; i < 2; ++i) {
                int mBase = m0 + wm + i * 16 + quad * 4;
#pragma unroll
                for (int r = 0; r < 4; ++r) {
                    float e = 0.f;
                    unsigned short w = 0;
                    if (valid) {
                        e = __expf(acc[i][j][r] + bsum);
                        w = f2b(e);
                        if (n == Rv) sfLastU[mBase + r] = e;
                    }
                    outB[(size_t)(mBase + r) * ldc + n] = w;
                    rsum[i][r] += e;
                }
            }
        }
        int slot = by * 2 + (wn >> 6);
#pragma unroll
        for (int i = 0; i < 2; ++i)
#pragma unroll
            for (int r = 0; r < 4; ++r) {
                float s = rsum[i][r];
                s += __shfl_xor(s, 1);
                s += __shfl_xor(s, 2);
                s += __shfl_xor(s, 4);
                s += __shfl_xor(s, 8);
                if (l16 == 0) {
                    int m = m0 + wm + i * 16 + quad * 4 + r;
                    rowPart[(size_t)m * RPSTRIDE + slot] = s;
                }
            }
        return;
    }

#pragma unroll
    for (int j = 0; j < 4; ++j) {
        int n = n0 + wn + j * 16 + l16;
        bool valid = (n < Ncols);
        if (!valid && bmode != 3) continue;
        float bsum = (valid && bias1) ? bias1[n] : 0.f;
#pragma unroll
        for (int i = 0; i < 2; ++i) {
            int mBase = m0 + wm + i * 16 + quad * 4;
#pragma unroll
            for (int r = 0; r < 4; ++r) {
                float v = acc[i][j][r] + bsum;
                size_t idx = (size_t)(mBase + r) * ldc + n;
                if (bmode == 0)      outF[idx] = v;
                else if (bmode == 3) outB[idx] = valid ? f2b(v) : (unsigned short)0;
                else                 outB[(size_t)bz * (Bv * Ev) + idx] = f2b(v);
            }
        }
    }
}

// ---------- full LSTM recurrence in ONE kernel (64 blocks x 16 batch rows) ----------
// Per step: gates = h_prev @ w_hh^T (B-frags direct from L2) + biasC + xg.
// h staged in padded LDS (intra-block barrier only); c in registers.
// t=0: pure epilogue (h=c=0). Steps t=0..6 (t=7 is dead in reference).
// t=1..5: also HW[t] = h_t @ W1a^T (fc1_w_b cols 0..255).  t=6: h -> hs6 global.
__global__ __launch_bounds__(256) void lstm_all(
    const unsigned short* __restrict__ w_hh_b,   // 1024 x 256 (gate-interleaved)
    const unsigned short* __restrict__ fc1_w_b,  // 256 x 512
    const float* __restrict__ biasC,             // 1024 (interleaved)
    const float* __restrict__ xg,                // (Bv*Lv) x 1024, row m*Lv+t
    unsigned short* __restrict__ hs6,            // 1024 x 256 (h at t=6)
    float* __restrict__ HW)                      // Lv x (Bv x 256), rows t=1..5 used
{
    __shared__ unsigned short hls[16 * HLS];     // 8.4 KB, pad-264 kills conflicts

    int mBase = blockIdx.x * 16;
    int tid  = threadIdx.x;
    int wave = tid >> 6;
    int lane = tid & 63;
    int quad = lane >> 4;
    int l16  = lane & 15;

    float c[4][4];                               // [ebl][r]: m=quad*4+r, e=ebg*16+l16
#pragma unroll
    for (int a = 0; a < 4; ++a)
#pragma unroll
        for (int b = 0; b < 4; ++b) c[a][b] = 0.f;

    for (int t = 0; t < 7; ++t) {
        f32x4 acc[4][4];                         // [ebl][gate]
#pragma unroll
        for (int a = 0; a < 4; ++a)
#pragma unroll
            for (int b = 0; b < 4; ++b) acc[a][b] = (f32x4){0.f, 0.f, 0.f, 0.f};

        if (t > 0) {
            bf16x8 af[8];
#pragma unroll
            for (int f = 0; f < 8; ++f)
                af[f] = *(const bf16x8*)(hls + l16 * HLS + f * 32 + quad * 8);
#pragma unroll
            for (int ebl = 0; ebl < 4; ++ebl)
#pragma unroll
                for (int g = 0; g < 4; ++g) {
                    int n = (wave * 16 + ebl * 4 + g) * 16 + l16;
                    const unsigned short* Bp = w_hh_b + (size_t)n * 256 + quad * 8;
                    f32x4 a4 = acc[ebl][g];
#pragma unroll
                    for (int f = 0; f < 8; ++f) {
                        bf16x8 b = *(const bf16x8*)(Bp + f * 32);
                        a4 = __builtin_amdgcn_mfma_f32_16x16x32_bf16(af[f], b, a4, 0, 0, 0);
                    }
                    acc[ebl][g] = a4;
                }
        }
        __syncthreads();                         // all hls reads done before overwrite

#pragma unroll
        for (int ebl = 0; ebl < 4; ++ebl) {
            int ebg = wave * 4 + ebl;
            int nb  = ebg * 64;
            float bi  = biasC[nb + l16];
            float bf_ = biasC[nb + 16 + l16];
            float bg  = biasC[nb + 32 + l16];
            float bo  = biasC[nb + 48 + l16];
#pragma unroll
            for (int r = 0; r < 4; ++r) {
                int m  = quad * 4 + r;
                int mg = mBase + m;
                const float* xr = xg + ((size_t)mg * Lv + t) * 1024 + nb + l16;
                float gi = acc[ebl][0][r] + bi  + xr[0];
                float gf = acc[ebl][1][r] + bf_ + xr[16];
                float gg = acc[ebl][2][r] + bg  + xr[32];
                float go = acc[ebl][3][r] + bo  + xr[48];
                float si = 1.f / (1.f + __expf(-gi));
                float sf = 1.f / (1.f + __expf(-gf));
                float so = 1.f / (1.f + __expf(-go));
                float cn = sf * c[ebl][r] + si * ftanh(gg);
                c[ebl][r] = cn;
                unsigned short hb = f2b(so * ftanh(cn));
                int e = ebg * 16 + l16;
                hls[m * HLS + e] = hb;
                if (t == 6) hs6[(size_t)mg * 256 + e] = hb;
            }
        }
        __syncthreads();                         // hls writes visible block-wide

        if (t >= 1 && t <= 5) {
            bf16x8 af[8];
#pragma unroll
            for (int f = 0; f < 8; ++f)
                af[f] = *(const bf16x8*)(hls + l16 * HLS + f * 32 + quad * 8);
#pragma unroll
            for (int j = 0; j < 4; ++j) {
                int n = wave * 64 + j * 16 + l16;
                const unsigned short* Bp = fc1_w_b + (size_t)n * 512 + quad * 8;
                f32x4 a4 = (f32x4){0.f, 0.f, 0.f, 0.f};
#pragma unroll
                for (int f = 0; f < 8; ++f) {
                    bf16x8 b = *(const bf16x8*)(Bp + f * 32);
                    a4 = __builtin_amdgcn_mfma_f32_16x16x32_bf16(af[f], b, a4, 0, 0, 0);
                }
#pragma unroll
                for (int r = 0; r < 4; ++r)
                    HW[(size_t)t * (Bv * Ev) + (size_t)(mBase + quad * 4 + r) * 256 + n]
                        = a4[r];
            }
        }
    }
}

// ---------- 64x64 tile GEMM (fc1), m97 schedule, BK=128 ----------
// mode&7: 1 bf16 relu. Ktot mult of 128.
__global__ __launch_bounds__(256) void gemm64(
    const unsigned short* __restrict__ A1, int lda1,
    const unsigned short* __restrict__ W1, int ldw1,
    const float* __restrict__ bias1,
    int Ktot, int Ncols, int mode,
    float* __restrict__ outF, unsigned short* __restrict__ outB,
    int ldc, int nshift,
    const float* __restrict__ xgate, int tstep)
{
    __shared__ unsigned short As[4][64 * 32];   // 4 x 4 KB
    __shared__ unsigned short Bs[4][64 * 32];   // 4 x 4 KB

    int bmode = mode & 7;
    int bx = blockIdx.x >> nshift;
    int by = blockIdx.x & ((1 << nshift) - 1);
    int tid  = threadIdx.x;
    int wave = tid >> 6;
    int lane = tid & 63;
    int quad = lane >> 4;
    int l16  = lane & 15;
    int m0 = bx * 64;
    int n0 = by * 64;

    f32x4 acc[4];
#pragma unroll
    for (int j = 0; j < 4; ++j) acc[j] = (f32x4){0.f, 0.f, 0.f, 0.f};

    int row = tid >> 2;
    int g8  = ((tid & 3) ^ (row & 3) ^ ((row >> 2) & 3)) * 8;

    bool first = true;
    for (int k = 0; k < Ktot; k += 128) {
        if (!first) __syncthreads();
        first = false;
#pragma unroll
        for (int h = 0; h < 4; ++h) {
            int kk = k + h * 32;
            glds16(A1 + (size_t)(m0 + row) * lda1 + kk + g8, As[h] + wave * 512);
            glds16(W1 + (size_t)(n0 + row) * ldw1 + kk + g8, Bs[h] + wave * 512);
        }
        asm volatile("s_waitcnt vmcnt(0)" ::: "memory");
        __syncthreads();

#pragma unroll
        for (int h = 0; h < 4; ++h) {
            int ml = wave * 16 + l16;
            int ca = quad ^ (ml & 3) ^ ((ml >> 2) & 3);
            bf16x8 a = *(const bf16x8*)(As[h] + ml * 32 + ca * 8);
#pragma unroll
            for (int j = 0; j < 4; ++j) {
                int nl = j * 16 + l16;
                int cb = quad ^ (nl & 3) ^ ((nl >> 2) & 3);
                bf16x8 b = *(const bf16x8*)(Bs[h] + nl * 32 + cb * 8);
                acc[j] = __builtin_amdgcn_mfma_f32_16x16x32_bf16(a, b, acc[j], 0, 0, 0);
            }
        }
    }

    (void)xgate; (void)tstep;
#pragma unroll
    for (int j = 0; j < 4; ++j) {
        int n = n0 + j * 16 + l16;
        if (n >= Ncols) continue;
        float bsum = bias1 ? bias1[n] : 0.f;
#pragma unroll
        for (int r = 0; r < 4; ++r) {
            int m = m0 + wave * 16 + quad * 4 + r;
            float v = acc[j][r] + bsum;
            if (bmode == 1) outB[(size_t)m * ldc + n] = f2b(v > 0.f ? v : 0.f);
            else            outB[(size_t)m * ldc + n] = f2b(v);
        }
    }
    (void)outF;
}

// merged prep (all input-only work)
__global__ void prep_k(const float* __restrict__ w_ih,
                       const float* __restrict__ w_hh,
                       const float* __restrict__ fc1_w,
                       const float* __restrict__ fc2_w,
                       const float* __restrict__ b_ih,
                       const float* __restrict__ b_hh,
                       const int* __restrict__ bodys,
                       const float* __restrict__ emb_w,
                       const float* __restrict__ fc1_b,
                       unsigned short* __restrict__ w_ih_b,
                       unsigned short* __restrict__ w_hh_b,
                       unsigned short* __restrict__ fc1_w_b,
                       unsigned short* __restrict__ fc2_w_b,
                       float* __restrict__ biasC,
                       unsigned short* __restrict__ x,
                       unsigned short* __restrict__ embT,
                       unsigned short* __restrict__ embc,
                       unsigned short* __restrict__ sfA,
                       float* __restrict__ B2,
                       unsigned short* __restrict__ emb_w_b,
                       unsigned short* __restrict__ EW1T)
{
    __shared__ float tile[32][33];
    int b = blockIdx.x, t = threadIdx.x;
    if (b < 1264) {                       // fc2: NPAD*Ev = 1264*2048
#pragma unroll
        for (int j = 0; j < 8; ++j) {
            int i = b * 2048 + j * 256 + t;
            fc2_w_b[i] = (i < NP1 * Ev) ? f2b(fc2_w[i]) : (unsigned short)0;
        }
    } else if (b < 1520) {                // w_ih / w_hh interleaved
        int bb = b - 1264;                // 0..255
        const float* src = (bb < 128) ? w_ih : w_hh;
        unsigned short* dst = (bb < 128) ? w_ih_b : w_hh_b;
        int rb = (bb & 127) * 8;
#pragma unroll
        for (int j = 0; j < 8; ++j) {
            int r = rb + j;
            int gate = (r >> 4) & 3;
            int e = (r & 15) | ((r >> 6) << 4);
            dst[(size_t)r * 256 + t] = f2b(src[(size_t)(gate * 256 + e) * 256 + t]);
        }
    } else if (b < 1584) {                // fc1: 64*2048 = 131072
        int base = (b - 1520) * 2048;
#pragma unroll
        for (int j = 0; j < 8; ++j) {
            int i = base + j * 256 + t;
            fc1_w_b[i] = f2b(fc1_w[i]);
        }
    } else if (b < 1585) {                // bias combine (interleaved)
#pragma unroll
        for (int j = 0; j < 4; ++j) {
            int r = j * 256 + t;
            int gate = (r >> 4) & 3;
            int e = (r & 15) | ((r >> 6) << 4);
            biasC[r] = b_ih[gate * 256 + e] + b_hh[gate * 256 + e];
        }
    } else if (b < 2609) {                // embed gather: 1024 blocks, 8 rows each
        int bb = b - 1585;
#pragma unroll
        for (int j = 0; j < 8; ++j) {
            int row = bb * 8 + j;
            x[(size_t)row * Ev + t] = f2b(emb_w[(size_t)bodys[row] * Ev + t]);
        }
    } else if (b < 5169) {                // emb transpose: 2560 = 320 kt x 8 et
        int bb = b - 2609;
        int kt = (bb % 320) * 32, et = (bb / 320) * 32;
        int tx = t & 31, ty = t >> 5;
#pragma unroll
        for (int r = ty; r < 32; r += 8) {
            int k = kt + r;
            tile[r][tx] = (k < Rv) ? emb_w[(size_t)k * Ev + et + tx] : 0.f;
        }
        __syncthreads();
#pragma unroll
        for (int r = ty; r < 32; r += 8) {
            embT[(size_t)(et + r) * PS2 + kt + tx] = f2b(tile[tx][r]);
        }
    } else if (b < 6193) {                // concat0 + sfA pad zero: 1024 blocks
        int bb = b - 5169;
        embc[(size_t)bb * 512 + t]       = f2b(emb_w[(size_t)bodys[bb * Lv + 0] * Ev + t]);
        embc[(size_t)bb * 512 + 256 + t] = f2b(emb_w[(size_t)bodys[bb * Lv + 1] * Ev + t]);
        if (t < PS2 - NPAD) sfA[(size_t)bb * PS2 + NPAD + t] = 0;
    } else if (b < 6200) {                // B2[i] = fc1_w[:,256:]@emb_w[i+1] + fc1_b
        int i = b - 6193;                 // 0..6
        const float* er = emb_w + (size_t)(i + 1) * Ev;
        const float* wr = fc1_w + (size_t)t * 512 + 256;
        float s = fc1_b[t];
        for (int k = 0; k < 256; ++k) s += wr[k] * er[k];
        B2[i * 256 + t] = s;
    } else if (b < 7464) {                // emb_w row-major bf16, pad rows zero
        int bb = b - 6200;                // 0..1263
#pragma unroll
        for (int j = 0; j < 8; ++j) {
            int i = bb * 2048 + j * 256 + t;
            emb_w_b[i] = ((i >> 8) < Rv) ? f2b(emb_w[i]) : (unsigned short)0;
        }
    } else {                              // EW1T pad cols [NPAD,PS2) zero: 128 blocks
        int idx = (b - 7464) * 256 + t;   // 0..32767
        EW1T[(size_t)(idx >> 7) * PS2 + NPAD + (idx & 127)] = 0;
    }
}

// finalize: sum NSLICE bf16 partials + rowsum-normalize.
// HWrow!=null (i=1..5): hiddenA <- relu(x1*inv + sfLastU*inv*HW + B2) directly.
// HWrow==null (i=6):    embc/outTail path (emb_1 materialized).
__global__ void finalize_emb(const unsigned short* __restrict__ emb1p,
                             const float* __restrict__ rowPart,
                             const float* __restrict__ sfLastU,
                             const unsigned short* __restrict__ h_i,
                             const float* __restrict__ emb_row,
                             unsigned short* __restrict__ embc,
                             float* __restrict__ outTail,
                             const float* __restrict__ HWrow,
                             const float* __restrict__ B2row,
                             unsigned short* __restrict__ hiddenA)
{
    int b = blockIdx.x, e = threadIdx.x;
    int wave = e >> 6, lane = e & 63;
    __shared__ float sred[4];
    float ps = (e < NSLOT) ? rowPart[(size_t)b * RPSTRIDE + e] : 0.f;
    for (int off = 32; off; off >>= 1) ps += __shfl_down(ps, off);
    if (lane == 0) sred[wave] = ps;
    __syncthreads();
    float inv = 1.f / (sred[0] + sred[1] + sred[2] + sred[3]);

    float x1 = 0.f;
#pragma unroll
    for (int z = 0; z < NSLICE; ++z)
        x1 += b2f(emb1p[(size_t)z * (Bv * Ev) + (size_t)b * Ev + e]);

    if (HWrow) {
        float v = x1 * inv + sfLastU[b] * inv * HWrow[(size_t)b * 256 + e] + B2row[e];
        hiddenA[(size_t)b * 256 + e] = f2b(v > 0.f ? v : 0.f);
    } else {
        float v = (x1 + sfLastU[b] * b2f(h_i[(size_t)b * Ev + e])) * inv;
        embc[(size_t)b * 512 + e] = f2b(v);
        float w = emb_row[e];
        embc[(size_t)b * 512 + 256 + e]    = f2b(w);
        outTail[(size_t)b * 512 + e]       = v;
        outTail[(size_t)b * 512 + 256 + e] = w;
    }
}

extern "C" void kernel_launch(void* const* d_in, const int* in_sizes, int n_in,
                              void* d_out, int out_size, void* d_ws, size_t ws_size,
                              hipStream_t stream)
{
    const int*   bodys = (const int*)d_in[0];
    const float* emb_w = (const float*)d_in[1];
    const float* w_ih  = (const float*)d_in[2];
    const float* w_hh  = (const float*)d_in[3];
    const float* b_ih  = (const float*)d_in[4];
    const float* b_hh  = (const float*)d_in[5];
    const float* fc1_w = (const float*)d_in[6];
    const float* fc1_b = (const float*)d_in[7];
    const float* fc2_w = (const float*)d_in[8];
    const float* fc2_b = (const float*)d_in[9];
    float* out = (float*)d_out;

    char* ws = (char*)d_ws;
    size_t off = 0;
    auto alloc = [&](size_t bytes) -> void* {
        void* p = ws + off;
        off += (bytes + 255) & ~(size_t)255;
        return p;
    };
    unsigned short* x       = (unsigned short*)alloc((size_t)Bv * Lv * Ev * 2);
    unsigned short* hs6     = (unsigned short*)alloc((size_t)Bv * Ev * 2);
    float*          xg      = (float*)alloc((size_t)Bv * Lv * 1024 * 4);   // 33.5 MB
    unsigned short* embT    = (unsigned short*)alloc((size_t)Ev * PS2 * 2);
    unsigned short* sfA     = (unsigned short*)alloc((size_t)Bv * PS2 * 2);
    float*          sfLastU = (float*)alloc((size_t)Bv * 4);
    float*          rowPart = (float*)alloc((size_t)Bv * RPSTRIDE * 4);
    unsigned short* emb1p   = (unsigned short*)alloc((size_t)NSLICE * Bv * Ev * 2);
    unsigned short* embc    = (unsigned short*)alloc((size_t)Bv * 512 * 2);
    unsigned short* hiddenA = (unsigned short*)alloc((size_t)Bv * Ev * 2);
    unsigned short* w_ih_b  = (unsigned short*)alloc((size_t)1024 * Ev * 2);
    unsigned short* w_hh_b  = (unsigned short*)alloc((size_t)1024 * Ev * 2);
    float*          biasC   = (float*)alloc((size_t)1024 * 4);
    float*          B2      = (float*)alloc((size_t)7 * 256 * 4);
    unsigned short* fc1_w_b = (unsigned short*)alloc((size_t)Ev * 512 * 2);
    unsigned short* fc2_w_b = (unsigned short*)alloc((size_t)NPAD * Ev * 2);
    unsigned short* emb_w_b = (unsigned short*)alloc((size_t)NPAD * Ev * 2);
    unsigned short* EW1T    = (unsigned short*)alloc((size_t)Ev * PS2 * 2);
    float*          HW      = (float*)alloc((size_t)Lv * Bv * Ev * 4);     // 8.4 MB
    (void)ws_size; (void)in_sizes; (void)n_in; (void)out_size;

    // all input-only prep in ONE launch
    prep_k<<<7592, 256, 0, stream>>>(w_ih, w_hh, fc1_w, fc2_w, b_ih, b_hh,
                                     bodys, emb_w, fc1_b,
                                     w_ih_b, w_hh_b, fc1_w_b, fc2_w_b, biasC, x,
                                     embT, embc, sfA, B2, emb_w_b, EW1T);

    // EW1T = (emb_w @ W1a^T)^T : M=256(e) x N=10112(r), K=256; bf16 zero-invalid
    gemm_tile<<<dim3(4, 79, 1), 256, 0, stream>>>(
        fc1_w_b, 512, emb_w_b, Ev,
        nullptr,
        Ev, Ev, Rv, 3,
        nullptr, EW1T, PS2, nullptr, nullptr);

    // fc1 for i=0 (depends only on prep's embc), K=512
    gemm64<<<64, 256, 0, stream>>>(
        embc, 512, fc1_w_b, 512,
        fc1_b,
        512, 256, 1,
        nullptr, hiddenA, 256, 2,
        nullptr, 0);

    // x-gate hoist: xg = x_all(8192x256) @ w_ih^T(1024x256) -> f32
    gemm_tile<<<dim3(128, 8, 1), 256, 0, stream>>>(
        x, Ev, w_ih_b, Ev,
        nullptr,
        Ev, Ev, 1024, 0,
        xg, nullptr, 1024, nullptr, nullptr);

    // full LSTM recurrence (7 steps, t=7 dead) + HW fusion in ONE launch
    lstm_all<<<64, 256, 0, stream>>>(w_hh_b, fc1_w_b, biasC, xg, hs6, HW);

    for (int i = 0; i < 7; ++i) {
        if (i > 0) {
            bool last = (i == 6);
            // X1/emb_1: sfA @ (EW1T | embT)^T -> 16 bf16 slices
            gemm_tile<<<512, 256, 0, stream>>>(
                sfA, PS2, last ? embT : EW1T, PS2,
                nullptr,
                PS2, PS2 / NSLICE, Ev, 2 | (2 << 4),
                nullptr, emb1p, Ev, nullptr, nullptr);
            finalize_emb<<<Bv, 256, 0, stream>>>(
                emb1p, rowPart, sfLastU,
                hs6, emb_w + (size_t)(i + 1) * Ev,
                embc, out + (size_t)Bv * NP1,
                last ? nullptr : (HW + (size_t)i * Bv * Ev),
                last ? nullptr : (B2 + (size_t)i * 256),
                hiddenA);
            if (last) {
                // fc1 for i=6 (emb_1 materialized; broadcast half via B2)
                gemm64<<<64, 256, 0, stream>>>(
                    embc, 512, fc1_w_b, 512,
                    B2 + (size_t)6 * 256,
                    256, 256, 1,
                    nullptr, hiddenA, 256, 2,
                    nullptr, 0);
            }
        }
        // fc2: prob = hidden(1024x256) @ fc2_w^T (swz=1)
        if (i < 6) {
            gemm_tile<<<1280, 256, 0, stream>>>(
                hiddenA, Ev, fc2_w_b, Ev,
                fc2_b,
                Ev, Ev, NP1, 5 | (1 << 4),
                nullptr, sfA, PS2, rowPart, sfLastU);
        } else {
            gemm_tile<<<1280, 256, 0, stream>>>(
                hiddenA, Ev, fc2_w_b, Ev,
                fc2_b,
                Ev, Ev, NP1, 0 | (1 << 4),
                out, nullptr, NP1, nullptr, nullptr);
        }
    }
}

// Round 16
// 434.171 us; speedup vs baseline: 1.3744x; 1.3744x over previous
//
#include <hip/hip_runtime.h>

#define Bv 1024
#define Ev 256
#define Lv 8
#define Rv 10000
#define NP1 10001
#define PS2 10240      // padded row stride (multiple of 2048)
#define NPAD 10112     // fc2 rows padded to 79*128
#define BM 64
#define BN 128
#define NSLICE 16
#define NSLOT 158      // 79 N-tiles * 2 wave-halves
#define RPSTRIDE 160   // padded slot stride for rowPart

typedef __attribute__((ext_vector_type(8))) short bf16x8;
typedef __attribute__((ext_vector_type(4))) float f32x4;

__device__ __forceinline__ float b2f(unsigned short u) {
    union { unsigned int i; float f; } v; v.i = ((unsigned int)u) << 16; return v.f;
}
__device__ __forceinline__ unsigned short f2b(float f) {
    union { float f; unsigned int i; } v; v.f = f;
    unsigned int r = v.i + 0x7fffu + ((v.i >> 16) & 1u);
    return (unsigned short)(r >> 16);
}
// fast tanh: (e-1)/(e+1), e=exp(2x); clamp keeps e finite (no inf/inf NaN)
__device__ __forceinline__ float ftanh(float x) {
    x = fminf(fmaxf(x, -30.f), 30.f);
    float e = __expf(2.f * x);
    return (e - 1.f) / (e + 1.f);
}
__device__ __forceinline__ void glds16(const void* g, void* l) {
    __builtin_amdgcn_global_load_lds(
        (const __attribute__((address_space(1))) void*)g,
        (__attribute__((address_space(3))) void*)l, 16, 0, 0);
}

// ---------- 64x128 tile GEMM, m97 schedule, BK=64 ----------
// mode&7: 0 f32 | 2 bf16 slice outB+bz*Bv*Ev | 3 bf16 zero-invalid | 5 exp+rowsums
// mode>>4 (XCD swizzle): 0 3-D grid | 1 fc2(1280, 1-D) | 2 emb1(512, 1-D, 16 slices)
__global__ __launch_bounds__(256) void gemm_tile(
    const unsigned short* __restrict__ A1, int lda1,
    const unsigned short* __restrict__ W1, int ldw1,
    const float* __restrict__ bias1,
    int Ktot, int kchunk, int Ncols, int mode,
    float* __restrict__ outF, unsigned short* __restrict__ outB, int ldc,
    float* __restrict__ rowPart, float* __restrict__ sfLastU)
{
    __shared__ unsigned short As[2][BM * 32];   // 2 x 4 KB
    __shared__ unsigned short Bs[2][BN * 32];   // 2 x 8 KB

    int bmode = mode & 7;
    int swz   = mode >> 4;
    int bx, by, bz;
    if (swz == 1) {            // fc2: same-N tiles share bid%8 -> same XCD
        int r = blockIdx.x & 7, q = blockIdx.x >> 3;   // q 0..159
        bx = q & 15; by = r + (q >> 4) * 8; bz = 0;
        if (by >= NPAD / BN) return;
    } else if (swz == 2) {     // emb1: same-K-slice shares bid%8 (16 slices)
        int r = blockIdx.x & 7, q = blockIdx.x >> 3;   // q 0..63
        bz = r + (q >> 5) * 8; bx = (q & 31) >> 1; by = q & 1;
    } else {
        bx = blockIdx.x; by = blockIdx.y; bz = blockIdx.z;
    }

    int tid  = threadIdx.x;
    int wave = tid >> 6;
    int lane = tid & 63;
    int quad = lane >> 4;
    int l16  = lane & 15;
    int wm = (wave & 1) * 32;
    int wn = (wave >> 1) * 64;
    int m0 = bx * BM;
    int n0 = by * BN;
    int k0 = bz * kchunk;
    int k1 = k0 + kchunk; if (k1 > Ktot) k1 = Ktot;   // kchunk mult of 64 here

    f32x4 acc[2][4];
#pragma unroll
    for (int i = 0; i < 2; ++i)
#pragma unroll
        for (int j = 0; j < 4; ++j) acc[i][j] = (f32x4){0.f, 0.f, 0.f, 0.f};

    int c0 = tid, c1 = 256 + tid;
    int row0 = c0 >> 2, row1 = c1 >> 2;
    int g80 = ((c0 & 3) ^ (row0 & 3) ^ ((row0 >> 2) & 3)) * 8;
    int g81 = ((c1 & 3) ^ (row1 & 3) ^ ((row1 >> 2) & 3)) * 8;

    bool first = true;
    for (int k = k0; k < k1; k += 64) {
        if (!first) __syncthreads();
        first = false;
#pragma unroll
        for (int h = 0; h < 2; ++h) {
            int kk = k + h * 32;
            glds16(A1 + (size_t)(m0 + row0) * lda1 + kk + g80, As[h] + (wave * 64) * 8);
            glds16(W1 + (size_t)(n0 + row0) * ldw1 + kk + g80, Bs[h] + (wave * 64) * 8);
            glds16(W1 + (size_t)(n0 + row1) * ldw1 + kk + g81, Bs[h] + (256 + wave * 64) * 8);
        }
        asm volatile("s_waitcnt vmcnt(0)" ::: "memory");
        __syncthreads();

#pragma unroll
        for (int h = 0; h < 2; ++h) {
            bf16x8 af[2], bfr[4];
#pragma unroll
            for (int t = 0; t < 2; ++t) {
                int m = wm + t * 16 + l16;
                int ca = quad ^ (m & 3) ^ ((m >> 2) & 3);
                af[t] = *(const bf16x8*)(As[h] + m * 32 + ca * 8);
            }
#pragma unroll
            for (int t = 0; t < 4; ++t) {
                int n = wn + t * 16 + l16;
                int cb = quad ^ (n & 3) ^ ((n >> 2) & 3);
                bfr[t] = *(const bf16x8*)(Bs[h] + n * 32 + cb * 8);
            }
#pragma unroll
            for (int i = 0; i < 2; ++i)
#pragma unroll
                for (int j = 0; j < 4; ++j)
                    acc[i][j] = __builtin_amdgcn_mfma_f32_16x16x32_bf16(
                        af[i], bfr[j], acc[i][j], 0, 0, 0);
        }
    }

    // D mapping: col = lane&15, row = quad*4 + reg
    if (bmode == 5) {
        // exp epilogue: sfA <- bf16(exp(logit)) (pad cols zeroed),
        // rowPart[m][by*2+half] <- partial row sum, sfLastU[m] <- exp at col Rv
        float rsum[2][4];
#pragma unroll
        for (int i = 0; i < 2; ++i)
#pragma unroll
            for (int r = 0; r < 4; ++r) rsum[i][r] = 0.f;
#pragma unroll
        for (int j = 0; j < 4; ++j) {
            int n = n0 + wn + j * 16 + l16;
            bool valid = (n < Ncols);
            float bsum = valid ? bias1[n] : 0.f;
#pragma unroll
            for (int i = 0; i < 2; ++i) {
                int mBase = m0 + wm + i * 16 + quad * 4;
#pragma unroll
                for (int r = 0; r < 4; ++r) {
                    float e = 0.f;
                    unsigned short w = 0;
                    if (valid) {
                        e = __expf(acc[i][j][r] + bsum);
                        w = f2b(e);
                        if (n == Rv) sfLastU[mBase + r] = e;
                    }
                    outB[(size_t)(mBase + r) * ldc + n] = w;
                    rsum[i][r] += e;
                }
            }
        }
        int slot = by * 2 + (wn >> 6);
#pragma unroll
        for (int i = 0; i < 2; ++i)
#pragma unroll
            for (int r = 0; r < 4; ++r) {
                float s = rsum[i][r];
                s += __shfl_xor(s, 1);
                s += __shfl_xor(s, 2);
                s += __shfl_xor(s, 4);
                s += __shfl_xor(s, 8);
                if (l16 == 0) {
                    int m = m0 + wm + i * 16 + quad * 4 + r;
                    rowPart[(size_t)m * RPSTRIDE + slot] = s;
                }
            }
        return;
    }

#pragma unroll
    for (int j = 0; j < 4; ++j) {
        int n = n0 + wn + j * 16 + l16;
        bool valid = (n < Ncols);
        if (!valid && bmode != 3) continue;
        float bsum = (valid && bias1) ? bias1[n] : 0.f;
#pragma unroll
        for (int i = 0; i < 2; ++i) {
            int mBase = m0 + wm + i * 16 + quad * 4;
#pragma unroll
            for (int r = 0; r < 4; ++r) {
                float v = acc[i][j][r] + bsum;
                size_t idx = (size_t)(mBase + r) * ldc + n;
                if (bmode == 0)      outF[idx] = v;
                else if (bmode == 3) outB[idx] = valid ? f2b(v) : (unsigned short)0;
                else                 outB[(size_t)bz * (Bv * Ev) + idx] = f2b(v);
            }
        }
    }
}

// ---------- 64x64 tile GEMM (LSTM / fc1), m97 schedule, BK=128 ----------
// mode&7: 1 bf16 relu | 4 LSTM gate epilogue (xgate f32, row m*8+tstep).
// mode&8: LSTM first step (c=0; Ktot=0 -> pure epilogue). Ktot mult of 128 (or 0).
__global__ __launch_bounds__(256) void gemm64(
    const unsigned short* __restrict__ A1, int lda1,
    const unsigned short* __restrict__ W1, int ldw1,
    const float* __restrict__ bias1,
    int Ktot, int Ncols, int mode,
    float* __restrict__ outF, unsigned short* __restrict__ outB,
    int ldc, int nshift,
    const float* __restrict__ xgate, int tstep)
{
    __shared__ unsigned short As[4][64 * 32];   // 4 x 4 KB
    __shared__ unsigned short Bs[4][64 * 32];   // 4 x 4 KB

    int bmode = mode & 7;
    int bx = blockIdx.x >> nshift;
    int by = blockIdx.x & ((1 << nshift) - 1);
    int tid  = threadIdx.x;
    int wave = tid >> 6;
    int lane = tid & 63;
    int quad = lane >> 4;
    int l16  = lane & 15;
    int m0 = bx * 64;
    int n0 = by * 64;

    f32x4 acc[4];
#pragma unroll
    for (int j = 0; j < 4; ++j) acc[j] = (f32x4){0.f, 0.f, 0.f, 0.f};

    int row = tid >> 2;
    int g8  = ((tid & 3) ^ (row & 3) ^ ((row >> 2) & 3)) * 8;

    bool first = true;
    for (int k = 0; k < Ktot; k += 128) {
        if (!first) __syncthreads();
        first = false;
#pragma unroll
        for (int h = 0; h < 4; ++h) {
            int kk = k + h * 32;
            glds16(A1 + (size_t)(m0 + row) * lda1 + kk + g8, As[h] + wave * 512);
            glds16(W1 + (size_t)(n0 + row) * ldw1 + kk + g8, Bs[h] + wave * 512);
        }
        asm volatile("s_waitcnt vmcnt(0)" ::: "memory");
        __syncthreads();

#pragma unroll
        for (int h = 0; h < 4; ++h) {
            int ml = wave * 16 + l16;
            int ca = quad ^ (ml & 3) ^ ((ml >> 2) & 3);
            bf16x8 a = *(const bf16x8*)(As[h] + ml * 32 + ca * 8);
#pragma unroll
            for (int j = 0; j < 4; ++j) {
                int nl = j * 16 + l16;
                int cb = quad ^ (nl & 3) ^ ((nl >> 2) & 3);
                bf16x8 b = *(const bf16x8*)(Bs[h] + nl * 32 + cb * 8);
                acc[j] = __builtin_amdgcn_mfma_f32_16x16x32_bf16(a, b, acc[j], 0, 0, 0);
            }
        }
    }

    if (bmode == 4) {
        // gate-interleaved cols: n = by*64 + gate*16 + l16 -> e = by*16 + l16
        int e  = by * 16 + l16;
        float bi = bias1[n0 + l16];
        float bf_ = bias1[n0 + 16 + l16];
        float bg = bias1[n0 + 32 + l16];
        float bo = bias1[n0 + 48 + l16];
#pragma unroll
        for (int r = 0; r < 4; ++r) {
            int m = m0 + wave * 16 + quad * 4 + r;
            const float* xr = xgate + ((size_t)m * Lv + tstep) * 1024 + n0 + l16;
            float gi = acc[0][r] + bi + xr[0];
            float gf = acc[1][r] + bf_ + xr[16];
            float gg = acc[2][r] + bg + xr[32];
            float go = acc[3][r] + bo + xr[48];
            float cp = (mode & 8) ? 0.f : outF[(size_t)m * 256 + e];
            float si = 1.f / (1.f + __expf(-gi));
            float sf = 1.f / (1.f + __expf(-gf));
            float so = 1.f / (1.f + __expf(-go));
            float cn = sf * cp + si * ftanh(gg);
            outF[(size_t)m * 256 + e] = cn;
            outB[(size_t)m * 256 + e] = f2b(so * ftanh(cn));
        }
        return;
    }

#pragma unroll
    for (int j = 0; j < 4; ++j) {
        int n = n0 + j * 16 + l16;
        if (n >= Ncols) continue;
        float bsum = bias1 ? bias1[n] : 0.f;
#pragma unroll
        for (int r = 0; r < 4; ++r) {
            int m = m0 + wave * 16 + quad * 4 + r;
            float v = acc[j][r] + bsum;
            if (bmode == 1) outB[(size_t)m * ldc + n] = f2b(v > 0.f ? v : 0.f);
            else            outB[(size_t)m * ldc + n] = f2b(v);
        }
    }
}

// merged prep (all input-only work)
__global__ void prep_k(const float* __restrict__ w_ih,
                       const float* __restrict__ w_hh,
                       const float* __restrict__ fc1_w,
                       const float* __restrict__ fc2_w,
                       const float* __restrict__ b_ih,
                       const float* __restrict__ b_hh,
                       const int* __restrict__ bodys,
                       const float* __restrict__ emb_w,
                       const float* __restrict__ fc1_b,
                       unsigned short* __restrict__ w_ih_b,
                       unsigned short* __restrict__ w_hh_b,
                       unsigned short* __restrict__ fc1_w_b,
                       unsigned short* __restrict__ fc2_w_b,
                       float* __restrict__ biasC,
                       unsigned short* __restrict__ x,
                       unsigned short* __restrict__ embT,
                       unsigned short* __restrict__ embc,
                       unsigned short* __restrict__ sfA,
                       float* __restrict__ B2,
                       unsigned short* __restrict__ emb_w_b,
                       unsigned short* __restrict__ EW1T)
{
    __shared__ float tile[32][33];
    int b = blockIdx.x, t = threadIdx.x;
    if (b < 1264) {                       // fc2: NPAD*Ev = 1264*2048
#pragma unroll
        for (int j = 0; j < 8; ++j) {
            int i = b * 2048 + j * 256 + t;
            fc2_w_b[i] = (i < NP1 * Ev) ? f2b(fc2_w[i]) : (unsigned short)0;
        }
    } else if (b < 1520) {                // w_ih / w_hh interleaved
        int bb = b - 1264;                // 0..255
        const float* src = (bb < 128) ? w_ih : w_hh;
        unsigned short* dst = (bb < 128) ? w_ih_b : w_hh_b;
        int rb = (bb & 127) * 8;
#pragma unroll
        for (int j = 0; j < 8; ++j) {
            int r = rb + j;
            int gate = (r >> 4) & 3;
            int e = (r & 15) | ((r >> 6) << 4);
            dst[(size_t)r * 256 + t] = f2b(src[(size_t)(gate * 256 + e) * 256 + t]);
        }
    } else if (b < 1584) {                // fc1: 64*2048 = 131072
        int base = (b - 1520) * 2048;
#pragma unroll
        for (int j = 0; j < 8; ++j) {
            int i = base + j * 256 + t;
            fc1_w_b[i] = f2b(fc1_w[i]);
        }
    } else if (b < 1585) {                // bias combine (interleaved)
#pragma unroll
        for (int j = 0; j < 4; ++j) {
            int r = j * 256 + t;
            int gate = (r >> 4) & 3;
            int e = (r & 15) | ((r >> 6) << 4);
            biasC[r] = b_ih[gate * 256 + e] + b_hh[gate * 256 + e];
        }
    } else if (b < 2609) {                // embed gather: 1024 blocks, 8 rows each
        int bb = b - 1585;
#pragma unroll
        for (int j = 0; j < 8; ++j) {
            int row = bb * 8 + j;
            x[(size_t)row * Ev + t] = f2b(emb_w[(size_t)bodys[row] * Ev + t]);
        }
    } else if (b < 5169) {                // emb transpose: 2560 = 320 kt x 8 et
        int bb = b - 2609;
        int kt = (bb % 320) * 32, et = (bb / 320) * 32;
        int tx = t & 31, ty = t >> 5;
#pragma unroll
        for (int r = ty; r < 32; r += 8) {
            int k = kt + r;
            tile[r][tx] = (k < Rv) ? emb_w[(size_t)k * Ev + et + tx] : 0.f;
        }
        __syncthreads();
#pragma unroll
        for (int r = ty; r < 32; r += 8) {
            embT[(size_t)(et + r) * PS2 + kt + tx] = f2b(tile[tx][r]);
        }
    } else if (b < 6193) {                // concat0 + sfA pad zero: 1024 blocks
        int bb = b - 5169;
        embc[(size_t)bb * 512 + t]       = f2b(emb_w[(size_t)bodys[bb * Lv + 0] * Ev + t]);
        embc[(size_t)bb * 512 + 256 + t] = f2b(emb_w[(size_t)bodys[bb * Lv + 1] * Ev + t]);
        if (t < PS2 - NPAD) sfA[(size_t)bb * PS2 + NPAD + t] = 0;
    } else if (b < 6200) {                // B2[i] = fc1_w[:,256:]@emb_w[i+1] + fc1_b
        int i = b - 6193;                 // 0..6
        const float* er = emb_w + (size_t)(i + 1) * Ev;
        const float* wr = fc1_w + (size_t)t * 512 + 256;
        float s = fc1_b[t];
        for (int k = 0; k < 256; ++k) s += wr[k] * er[k];
        B2[i * 256 + t] = s;
    } else if (b < 7464) {                // emb_w row-major bf16, pad rows zero
        int bb = b - 6200;                // 0..1263
#pragma unroll
        for (int j = 0; j < 8; ++j) {
            int i = bb * 2048 + j * 256 + t;
            emb_w_b[i] = ((i >> 8) < Rv) ? f2b(emb_w[i]) : (unsigned short)0;
        }
    } else {                              // EW1T pad cols [NPAD,PS2) zero: 128 blocks
        int idx = (b - 7464) * 256 + t;   // 0..32767
        EW1T[(size_t)(idx >> 7) * PS2 + NPAD + (idx & 127)] = 0;
    }
}

// finalize: sum NSLICE bf16 partials + rowsum-normalize.
// HWrow!=null (i=1..5): hiddenA <- relu(x1*inv + sfLastU*inv*HW + B2) directly.
// HWrow==null (i=6):    embc/outTail path (emb_1 materialized).
__global__ void finalize_emb(const unsigned short* __restrict__ emb1p,
                             const float* __restrict__ rowPart,
                             const float* __restrict__ sfLastU,
                             const unsigned short* __restrict__ h_i,
                             const float* __restrict__ emb_row,
                             unsigned short* __restrict__ embc,
                             float* __restrict__ outTail,
                             const float* __restrict__ HWrow,
                             const float* __restrict__ B2row,
                             unsigned short* __restrict__ hiddenA)
{
    int b = blockIdx.x, e = threadIdx.x;
    int wave = e >> 6, lane = e & 63;
    __shared__ float sred[4];
    float ps = (e < NSLOT) ? rowPart[(size_t)b * RPSTRIDE + e] : 0.f;
    for (int off = 32; off; off >>= 1) ps += __shfl_down(ps, off);
    if (lane == 0) sred[wave] = ps;
    __syncthreads();
    float inv = 1.f / (sred[0] + sred[1] + sred[2] + sred[3]);

    float x1 = 0.f;
#pragma unroll
    for (int z = 0; z < NSLICE; ++z)
        x1 += b2f(emb1p[(size_t)z * (Bv * Ev) + (size_t)b * Ev + e]);

    if (HWrow) {
        float v = x1 * inv + sfLastU[b] * inv * HWrow[(size_t)b * 256 + e] + B2row[e];
        hiddenA[(size_t)b * 256 + e] = f2b(v > 0.f ? v : 0.f);
    } else {
        float v = (x1 + sfLastU[b] * b2f(h_i[(size_t)b * Ev + e])) * inv;
        embc[(size_t)b * 512 + e] = f2b(v);
        float w = emb_row[e];
        embc[(size_t)b * 512 + 256 + e]    = f2b(w);
        outTail[(size_t)b * 512 + e]       = v;
        outTail[(size_t)b * 512 + 256 + e] = w;
    }
}

extern "C" void kernel_launch(void* const* d_in, const int* in_sizes, int n_in,
                              void* d_out, int out_size, void* d_ws, size_t ws_size,
                              hipStream_t stream)
{
    const int*   bodys = (const int*)d_in[0];
    const float* emb_w = (const float*)d_in[1];
    const float* w_ih  = (const float*)d_in[2];
    const float* w_hh  = (const float*)d_in[3];
    const float* b_ih  = (const float*)d_in[4];
    const float* b_hh  = (const float*)d_in[5];
    const float* fc1_w = (const float*)d_in[6];
    const float* fc1_b = (const float*)d_in[7];
    const float* fc2_w = (const float*)d_in[8];
    const float* fc2_b = (const float*)d_in[9];
    float* out = (float*)d_out;

    char* ws = (char*)d_ws;
    size_t off = 0;
    auto alloc = [&](size_t bytes) -> void* {
        void* p = ws + off;
        off += (bytes + 255) & ~(size_t)255;
        return p;
    };
    unsigned short* x       = (unsigned short*)alloc((size_t)Bv * Lv * Ev * 2);
    unsigned short* hs      = (unsigned short*)alloc((size_t)Lv * Bv * Ev * 2);
    float*          cbuf    = (float*)alloc((size_t)Bv * Ev * 4);
    float*          xg      = (float*)alloc((size_t)Bv * Lv * 1024 * 4);   // 33.5 MB
    unsigned short* embT    = (unsigned short*)alloc((size_t)Ev * PS2 * 2);
    unsigned short* sfA     = (unsigned short*)alloc((size_t)Bv * PS2 * 2);
    float*          sfLastU = (float*)alloc((size_t)Bv * 4);
    float*          rowPart = (float*)alloc((size_t)Bv * RPSTRIDE * 4);
    unsigned short* emb1p   = (unsigned short*)alloc((size_t)NSLICE * Bv * Ev * 2);
    unsigned short* embc    = (unsigned short*)alloc((size_t)Bv * 512 * 2);
    unsigned short* hiddenA = (unsigned short*)alloc((size_t)Bv * Ev * 2);
    unsigned short* w_ih_b  = (unsigned short*)alloc((size_t)1024 * Ev * 2);
    unsigned short* w_hh_b  = (unsigned short*)alloc((size_t)1024 * Ev * 2);
    float*          biasC   = (float*)alloc((size_t)1024 * 4);
    float*          B2      = (float*)alloc((size_t)7 * 256 * 4);
    unsigned short* fc1_w_b = (unsigned short*)alloc((size_t)Ev * 512 * 2);
    unsigned short* fc2_w_b = (unsigned short*)alloc((size_t)NPAD * Ev * 2);
    unsigned short* emb_w_b = (unsigned short*)alloc((size_t)NPAD * Ev * 2);
    unsigned short* EW1T    = (unsigned short*)alloc((size_t)Ev * PS2 * 2);
    float*          HW      = (float*)alloc((size_t)Lv * Bv * Ev * 4);     // 8.4 MB
    (void)ws_size; (void)in_sizes; (void)n_in; (void)out_size;

    // all input-only prep in ONE launch
    prep_k<<<7592, 256, 0, stream>>>(w_ih, w_hh, fc1_w, fc2_w, b_ih, b_hh,
                                     bodys, emb_w, fc1_b,
                                     w_ih_b, w_hh_b, fc1_w_b, fc2_w_b, biasC, x,
                                     embT, embc, sfA, B2, emb_w_b, EW1T);

    // EW1T = (emb_w @ W1a^T)^T : M=256(e) x N=10112(r), K=256; bf16 zero-invalid
    gemm_tile<<<dim3(4, 79, 1), 256, 0, stream>>>(
        fc1_w_b, 512, emb_w_b, Ev,
        nullptr,
        Ev, Ev, Rv, 3,
        nullptr, EW1T, PS2, nullptr, nullptr);

    // fc1 for i=0 (depends only on prep's embc), K=512
    gemm64<<<64, 256, 0, stream>>>(
        embc, 512, fc1_w_b, 512,
        fc1_b,
        512, 256, 1,
        nullptr, hiddenA, 256, 2,
        nullptr, 0);

    // x-gate hoist: xg = x_all(8192x256) @ w_ih^T(1024x256) -> f32
    gemm_tile<<<dim3(128, 8, 1), 256, 0, stream>>>(
        x, Ev, w_ih_b, Ev,
        nullptr,
        Ev, Ev, 1024, 0,
        xg, nullptr, 1024, nullptr, nullptr);

    // LSTM recurrence: 8 steps, h@w_hh only (t=0: Ktot=0, pure epilogue)
    // Ktot=256 is a mult of 128 -> 2 staged super-steps per launch
    for (int t = 0; t < Lv; ++t) {
        gemm64<<<256, 256, 0, stream>>>(
            hs + (size_t)(t ? t - 1 : 0) * Bv * Ev, Ev, w_hh_b, Ev,
            biasC,
            (t == 0) ? 0 : Ev, 1024, 4 | (t == 0 ? 8 : 0),
            cbuf, hs + (size_t)t * Bv * Ev, 1024, 4,
            xg, t);
    }

    // HW = hs(8192x256) @ W1a^T(256x256) -> f32
    gemm_tile<<<dim3(128, 2, 1), 256, 0, stream>>>(
        hs, Ev, fc1_w_b, 512,
        nullptr,
        Ev, Ev, Ev, 0,
        HW, nullptr, Ev, nullptr, nullptr);

    for (int i = 0; i < 7; ++i) {
        if (i > 0) {
            bool last = (i == 6);
            // X1/emb_1: sfA @ (EW1T | embT)^T -> 16 bf16 slices
            gemm_tile<<<512, 256, 0, stream>>>(
                sfA, PS2, last ? embT : EW1T, PS2,
                nullptr,
                PS2, PS2 / NSLICE, Ev, 2 | (2 << 4),
                nullptr, emb1p, Ev, nullptr, nullptr);
            finalize_emb<<<Bv, 256, 0, stream>>>(
                emb1p, rowPart, sfLastU,
                hs + (size_t)i * Bv * Ev, emb_w + (size_t)(i + 1) * Ev,
                embc, out + (size_t)Bv * NP1,
                last ? nullptr : (HW + (size_t)i * Bv * Ev),
                last ? nullptr : (B2 + (size_t)i * 256),
                hiddenA);
            if (last) {
                // fc1 for i=6 (emb_1 materialized; broadcast half via B2)
                gemm64<<<64, 256, 0, stream>>>(
                    embc, 512, fc1_w_b, 512,
                    B2 + (size_t)6 * 256,
                    256, 256, 1,
                    nullptr, hiddenA, 256, 2,
                    nullptr, 0);
            }
        }
        // fc2: prob = hidden(1024x256) @ fc2_w^T (swz=1)
        if (i < 6) {
            gemm_tile<<<1280, 256, 0, stream>>>(
                hiddenA, Ev, fc2_w_b, Ev,
                fc2_b,
                Ev, Ev, NP1, 5 | (1 << 4),
                nullptr, sfA, PS2, rowPart, sfLastU);
        } else {
            gemm_tile<<<1280, 256, 0, stream>>>(
                hiddenA, Ev, fc2_w_b, Ev,
                fc2_b,
                Ev, Ev, NP1, 0 | (1 << 4),
                out, nullptr, NP1, nullptr, nullptr);
        }
    }
}

// Round 17
// 425.755 us; speedup vs baseline: 1.4016x; 1.0198x over previous
//
#include <hip/hip_runtime.h>

#define Bv 1024
#define Ev 256
#define Lv 8
#define Rv 10000
#define NP1 10001
#define PS2 10240      // padded row stride (multiple of 2048)
#define NPAD 10112     // fc2 rows padded to 79*128
#define BM 64
#define BN 128
#define NSLICE 16
#define NSLOT 158      // 79 N-tiles * 2 wave-halves
#define RPSTRIDE 160   // padded slot stride for rowPart

typedef __attribute__((ext_vector_type(8))) short bf16x8;
typedef __attribute__((ext_vector_type(4))) float f32x4;

__device__ __forceinline__ float b2f(unsigned short u) {
    union { unsigned int i; float f; } v; v.i = ((unsigned int)u) << 16; return v.f;
}
__device__ __forceinline__ unsigned short f2b(float f) {
    union { float f; unsigned int i; } v; v.f = f;
    unsigned int r = v.i + 0x7fffu + ((v.i >> 16) & 1u);
    return (unsigned short)(r >> 16);
}
// fast tanh: (e-1)/(e+1), e=exp(2x); clamp keeps e finite (no inf/inf NaN)
__device__ __forceinline__ float ftanh(float x) {
    x = fminf(fmaxf(x, -30.f), 30.f);
    float e = __expf(2.f * x);
    return (e - 1.f) / (e + 1.f);
}
__device__ __forceinline__ void glds16(const void* g, void* l) {
    __builtin_amdgcn_global_load_lds(
        (const __attribute__((address_space(1))) void*)g,
        (__attribute__((address_space(3))) void*)l, 16, 0, 0);
}

// ---------- 64x128 tile GEMM, m97 schedule, BK=64 ----------
// mode&7: 0 f32 | 2 bf16 slice outB+bz*Bv*Ev | 3 bf16 zero-invalid | 5 exp+rowsums
// mode>>4 (XCD swizzle): 0 3-D grid | 1 fc2(1280, 1-D) | 2 emb1(512, 1-D, 16 slices)
__global__ __launch_bounds__(256) void gemm_tile(
    const unsigned short* __restrict__ A1, int lda1,
    const unsigned short* __restrict__ W1, int ldw1,
    const float* __restrict__ bias1,
    int Ktot, int kchunk, int Ncols, int mode,
    float* __restrict__ outF, unsigned short* __restrict__ outB, int ldc,
    float* __restrict__ rowPart, float* __restrict__ sfLastU)
{
    __shared__ unsigned short As[2][BM * 32];   // 2 x 4 KB
    __shared__ unsigned short Bs[2][BN * 32];   // 2 x 8 KB

    int bmode = mode & 7;
    int swz   = mode >> 4;
    int bx, by, bz;
    if (swz == 1) {            // fc2: same-N tiles share bid%8 -> same XCD
        int r = blockIdx.x & 7, q = blockIdx.x >> 3;   // q 0..159
        bx = q & 15; by = r + (q >> 4) * 8; bz = 0;
        if (by >= NPAD / BN) return;
    } else if (swz == 2) {     // emb1: same-K-slice shares bid%8 (16 slices)
        int r = blockIdx.x & 7, q = blockIdx.x >> 3;   // q 0..63
        bz = r + (q >> 5) * 8; bx = (q & 31) >> 1; by = q & 1;
    } else {
        bx = blockIdx.x; by = blockIdx.y; bz = blockIdx.z;
    }

    int tid  = threadIdx.x;
    int wave = tid >> 6;
    int lane = tid & 63;
    int quad = lane >> 4;
    int l16  = lane & 15;
    int wm = (wave & 1) * 32;
    int wn = (wave >> 1) * 64;
    int m0 = bx * BM;
    int n0 = by * BN;
    int k0 = bz * kchunk;
    int k1 = k0 + kchunk; if (k1 > Ktot) k1 = Ktot;   // kchunk mult of 64 here

    f32x4 acc[2][4];
#pragma unroll
    for (int i = 0; i < 2; ++i)
#pragma unroll
        for (int j = 0; j < 4; ++j) acc[i][j] = (f32x4){0.f, 0.f, 0.f, 0.f};

    int c0 = tid, c1 = 256 + tid;
    int row0 = c0 >> 2, row1 = c1 >> 2;
    int g80 = ((c0 & 3) ^ (row0 & 3) ^ ((row0 >> 2) & 3)) * 8;
    int g81 = ((c1 & 3) ^ (row1 & 3) ^ ((row1 >> 2) & 3)) * 8;

    bool first = true;
    for (int k = k0; k < k1; k += 64) {
        if (!first) __syncthreads();
        first = false;
#pragma unroll
        for (int h = 0; h < 2; ++h) {
            int kk = k + h * 32;
            glds16(A1 + (size_t)(m0 + row0) * lda1 + kk + g80, As[h] + (wave * 64) * 8);
            glds16(W1 + (size_t)(n0 + row0) * ldw1 + kk + g80, Bs[h] + (wave * 64) * 8);
            glds16(W1 + (size_t)(n0 + row1) * ldw1 + kk + g81, Bs[h] + (256 + wave * 64) * 8);
        }
        asm volatile("s_waitcnt vmcnt(0)" ::: "memory");
        __syncthreads();

#pragma unroll
        for (int h = 0; h < 2; ++h) {
            bf16x8 af[2], bfr[4];
#pragma unroll
            for (int t = 0; t < 2; ++t) {
                int m = wm + t * 16 + l16;
                int ca = quad ^ (m & 3) ^ ((m >> 2) & 3);
                af[t] = *(const bf16x8*)(As[h] + m * 32 + ca * 8);
            }
#pragma unroll
            for (int t = 0; t < 4; ++t) {
                int n = wn + t * 16 + l16;
                int cb = quad ^ (n & 3) ^ ((n >> 2) & 3);
                bfr[t] = *(const bf16x8*)(Bs[h] + n * 32 + cb * 8);
            }
#pragma unroll
            for (int i = 0; i < 2; ++i)
#pragma unroll
                for (int j = 0; j < 4; ++j)
                    acc[i][j] = __builtin_amdgcn_mfma_f32_16x16x32_bf16(
                        af[i], bfr[j], acc[i][j], 0, 0, 0);
        }
    }

    // D mapping: col = lane&15, row = quad*4 + reg
    if (bmode == 5) {
        // exp epilogue: sfA <- bf16(exp(logit)) (pad cols zeroed),
        // rowPart[m][by*2+half] <- partial row sum, sfLastU[m] <- exp at col Rv
        float rsum[2][4];
#pragma unroll
        for (int i = 0; i < 2; ++i)
#pragma unroll
            for (int r = 0; r < 4; ++r) rsum[i][r] = 0.f;
#pragma unroll
        for (int j = 0; j < 4; ++j) {
            int n = n0 + wn + j * 16 + l16;
            bool valid = (n < Ncols);
            float bsum = valid ? bias1[n] : 0.f;
#pragma unroll
            for (int i = 0; i < 2; ++i) {
                int mBase = m0 + wm + i * 16 + quad * 4;
#pragma unroll
                for (int r = 0; r < 4; ++r) {
                    float e = 0.f;
                    unsigned short w = 0;
                    if (valid) {
                        e = __expf(acc[i][j][r] + bsum);
                        w = f2b(e);
                        if (n == Rv) sfLastU[mBase + r] = e;
                    }
                    outB[(size_t)(mBase + r) * ldc + n] = w;
                    rsum[i][r] += e;
                }
            }
        }
        int slot = by * 2 + (wn >> 6);
#pragma unroll
        for (int i = 0; i < 2; ++i)
#pragma unroll
            for (int r = 0; r < 4; ++r) {
                float s = rsum[i][r];
                s += __shfl_xor(s, 1);
                s += __shfl_xor(s, 2);
                s += __shfl_xor(s, 4);
                s += __shfl_xor(s, 8);
                if (l16 == 0) {
                    int m = m0 + wm + i * 16 + quad * 4 + r;
                    rowPart[(size_t)m * RPSTRIDE + slot] = s;
                }
            }
        return;
    }

#pragma unroll
    for (int j = 0; j < 4; ++j) {
        int n = n0 + wn + j * 16 + l16;
        bool valid = (n < Ncols);
        if (!valid && bmode != 3) continue;
        float bsum = (valid && bias1) ? bias1[n] : 0.f;
#pragma unroll
        for (int i = 0; i < 2; ++i) {
            int mBase = m0 + wm + i * 16 + quad * 4;
#pragma unroll
            for (int r = 0; r < 4; ++r) {
                float v = acc[i][j][r] + bsum;
                size_t idx = (size_t)(mBase + r) * ldc + n;
                if (bmode == 0)      outF[idx] = v;
                else if (bmode == 3) outB[idx] = valid ? f2b(v) : (unsigned short)0;
                else                 outB[(size_t)bz * (Bv * Ev) + idx] = f2b(v);
            }
        }
    }
}

// ---------- 64x64 tile GEMM (LSTM / fc1), m97 schedule, BK=128 ----------
// mode&7: 1 bf16 relu | 4 LSTM gate epilogue (xgate f32, row m*8+tstep).
// mode&8: LSTM first step (c=0; Ktot=0 -> pure epilogue). Ktot mult of 128 (or 0).
__global__ __launch_bounds__(256) void gemm64(
    const unsigned short* __restrict__ A1, int lda1,
    const unsigned short* __restrict__ W1, int ldw1,
    const float* __restrict__ bias1,
    int Ktot, int Ncols, int mode,
    float* __restrict__ outF, unsigned short* __restrict__ outB,
    int ldc, int nshift,
    const float* __restrict__ xgate, int tstep)
{
    __shared__ unsigned short As[4][64 * 32];   // 4 x 4 KB
    __shared__ unsigned short Bs[4][64 * 32];   // 4 x 4 KB

    int bmode = mode & 7;
    int bx = blockIdx.x >> nshift;
    int by = blockIdx.x & ((1 << nshift) - 1);
    int tid  = threadIdx.x;
    int wave = tid >> 6;
    int lane = tid & 63;
    int quad = lane >> 4;
    int l16  = lane & 15;
    int m0 = bx * 64;
    int n0 = by * 64;

    f32x4 acc[4];
#pragma unroll
    for (int j = 0; j < 4; ++j) acc[j] = (f32x4){0.f, 0.f, 0.f, 0.f};

    int row = tid >> 2;
    int g8  = ((tid & 3) ^ (row & 3) ^ ((row >> 2) & 3)) * 8;

    bool first = true;
    for (int k = 0; k < Ktot; k += 128) {
        if (!first) __syncthreads();
        first = false;
#pragma unroll
        for (int h = 0; h < 4; ++h) {
            int kk = k + h * 32;
            glds16(A1 + (size_t)(m0 + row) * lda1 + kk + g8, As[h] + wave * 512);
            glds16(W1 + (size_t)(n0 + row) * ldw1 + kk + g8, Bs[h] + wave * 512);
        }
        asm volatile("s_waitcnt vmcnt(0)" ::: "memory");
        __syncthreads();

#pragma unroll
        for (int h = 0; h < 4; ++h) {
            int ml = wave * 16 + l16;
            int ca = quad ^ (ml & 3) ^ ((ml >> 2) & 3);
            bf16x8 a = *(const bf16x8*)(As[h] + ml * 32 + ca * 8);
#pragma unroll
            for (int j = 0; j < 4; ++j) {
                int nl = j * 16 + l16;
                int cb = quad ^ (nl & 3) ^ ((nl >> 2) & 3);
                bf16x8 b = *(const bf16x8*)(Bs[h] + nl * 32 + cb * 8);
                acc[j] = __builtin_amdgcn_mfma_f32_16x16x32_bf16(a, b, acc[j], 0, 0, 0);
            }
        }
    }

    if (bmode == 4) {
        // gate-interleaved cols: n = by*64 + gate*16 + l16 -> e = by*16 + l16
        int e  = by * 16 + l16;
        float bi = bias1[n0 + l16];
        float bf_ = bias1[n0 + 16 + l16];
        float bg = bias1[n0 + 32 + l16];
        float bo = bias1[n0 + 48 + l16];
#pragma unroll
        for (int r = 0; r < 4; ++r) {
            int m = m0 + wave * 16 + quad * 4 + r;
            const float* xr = xgate + ((size_t)m * Lv + tstep) * 1024 + n0 + l16;
            float gi = acc[0][r] + bi + xr[0];
            float gf = acc[1][r] + bf_ + xr[16];
            float gg = acc[2][r] + bg + xr[32];
            float go = acc[3][r] + bo + xr[48];
            float cp = (mode & 8) ? 0.f : outF[(size_t)m * 256 + e];
            float si = 1.f / (1.f + __expf(-gi));
            float sf = 1.f / (1.f + __expf(-gf));
            float so = 1.f / (1.f + __expf(-go));
            float cn = sf * cp + si * ftanh(gg);
            outF[(size_t)m * 256 + e] = cn;
            outB[(size_t)m * 256 + e] = f2b(so * ftanh(cn));
        }
        return;
    }

#pragma unroll
    for (int j = 0; j < 4; ++j) {
        int n = n0 + j * 16 + l16;
        if (n >= Ncols) continue;
        float bsum = bias1 ? bias1[n] : 0.f;
#pragma unroll
        for (int r = 0; r < 4; ++r) {
            int m = m0 + wave * 16 + quad * 4 + r;
            float v = acc[j][r] + bsum;
            if (bmode == 1) outB[(size_t)m * ldc + n] = f2b(v > 0.f ? v : 0.f);
            else            outB[(size_t)m * ldc + n] = f2b(v);
        }
    }
}

// merged prep (all input-only work)
__global__ void prep_k(const float* __restrict__ w_ih,
                       const float* __restrict__ w_hh,
                       const float* __restrict__ fc1_w,
                       const float* __restrict__ fc2_w,
                       const float* __restrict__ b_ih,
                       const float* __restrict__ b_hh,
                       const int* __restrict__ bodys,
                       const float* __restrict__ emb_w,
                       const float* __restrict__ fc1_b,
                       unsigned short* __restrict__ w_ih_b,
                       unsigned short* __restrict__ w_hh_b,
                       unsigned short* __restrict__ fc1_w_b,
                       unsigned short* __restrict__ fc2_w_b,
                       float* __restrict__ biasC,
                       unsigned short* __restrict__ x,
                       unsigned short* __restrict__ embT,
                       unsigned short* __restrict__ embc,
                       unsigned short* __restrict__ sfA,
                       float* __restrict__ B2,
                       unsigned short* __restrict__ emb_w_b,
                       unsigned short* __restrict__ EW1T)
{
    __shared__ float tile[32][33];
    int b = blockIdx.x, t = threadIdx.x;
    if (b < 1264) {                       // fc2: NPAD*Ev = 1264*2048
#pragma unroll
        for (int j = 0; j < 8; ++j) {
            int i = b * 2048 + j * 256 + t;
            fc2_w_b[i] = (i < NP1 * Ev) ? f2b(fc2_w[i]) : (unsigned short)0;
        }
    } else if (b < 1520) {                // w_ih / w_hh interleaved
        int bb = b - 1264;                // 0..255
        const float* src = (bb < 128) ? w_ih : w_hh;
        unsigned short* dst = (bb < 128) ? w_ih_b : w_hh_b;
        int rb = (bb & 127) * 8;
#pragma unroll
        for (int j = 0; j < 8; ++j) {
            int r = rb + j;
            int gate = (r >> 4) & 3;
            int e = (r & 15) | ((r >> 6) << 4);
            dst[(size_t)r * 256 + t] = f2b(src[(size_t)(gate * 256 + e) * 256 + t]);
        }
    } else if (b < 1584) {                // fc1: 64*2048 = 131072
        int base = (b - 1520) * 2048;
#pragma unroll
        for (int j = 0; j < 8; ++j) {
            int i = base + j * 256 + t;
            fc1_w_b[i] = f2b(fc1_w[i]);
        }
    } else if (b < 1585) {                // bias combine (interleaved)
#pragma unroll
        for (int j = 0; j < 4; ++j) {
            int r = j * 256 + t;
            int gate = (r >> 4) & 3;
            int e = (r & 15) | ((r >> 6) << 4);
            biasC[r] = b_ih[gate * 256 + e] + b_hh[gate * 256 + e];
        }
    } else if (b < 2609) {                // embed gather: 1024 blocks, 8 rows each
        int bb = b - 1585;
#pragma unroll
        for (int j = 0; j < 8; ++j) {
            int row = bb * 8 + j;
            x[(size_t)row * Ev + t] = f2b(emb_w[(size_t)bodys[row] * Ev + t]);
        }
    } else if (b < 5169) {                // emb transpose: 2560 = 320 kt x 8 et
        int bb = b - 2609;
        int kt = (bb % 320) * 32, et = (bb / 320) * 32;
        int tx = t & 31, ty = t >> 5;
#pragma unroll
        for (int r = ty; r < 32; r += 8) {
            int k = kt + r;
            tile[r][tx] = (k < Rv) ? emb_w[(size_t)k * Ev + et + tx] : 0.f;
        }
        __syncthreads();
#pragma unroll
        for (int r = ty; r < 32; r += 8) {
            embT[(size_t)(et + r) * PS2 + kt + tx] = f2b(tile[tx][r]);
        }
    } else if (b < 6193) {                // concat0 + sfA pad zero: 1024 blocks
        int bb = b - 5169;
        embc[(size_t)bb * 512 + t]       = f2b(emb_w[(size_t)bodys[bb * Lv + 0] * Ev + t]);
        embc[(size_t)bb * 512 + 256 + t] = f2b(emb_w[(size_t)bodys[bb * Lv + 1] * Ev + t]);
        if (t < PS2 - NPAD) sfA[(size_t)bb * PS2 + NPAD + t] = 0;
    } else if (b < 6200) {                // B2[i] = fc1_w[:,256:]@emb_w[i+1] + fc1_b
        int i = b - 6193;                 // 0..6
        const float* er = emb_w + (size_t)(i + 1) * Ev;
        const float* wr = fc1_w + (size_t)t * 512 + 256;
        float s = fc1_b[t];
        for (int k = 0; k < 256; ++k) s += wr[k] * er[k];
        B2[i * 256 + t] = s;
    } else if (b < 7464) {                // emb_w row-major bf16, pad rows zero
        int bb = b - 6200;                // 0..1263
#pragma unroll
        for (int j = 0; j < 8; ++j) {
            int i = bb * 2048 + j * 256 + t;
            emb_w_b[i] = ((i >> 8) < Rv) ? f2b(emb_w[i]) : (unsigned short)0;
        }
    } else {                              // EW1T pad cols [NPAD,PS2) zero: 128 blocks
        int idx = (b - 7464) * 256 + t;   // 0..32767
        EW1T[(size_t)(idx >> 7) * PS2 + NPAD + (idx & 127)] = 0;
    }
}

// finalize: sum NSLICE bf16 partials + rowsum-normalize.
// HWrow!=null (i=1..5): hiddenA <- relu(x1*inv + sfLastU*inv*HW + B2) directly.
// HWrow==null (i=6):    embc/outTail path (emb_1 materialized).
__global__ void finalize_emb(const unsigned short* __restrict__ emb1p,
                             const float* __restrict__ rowPart,
                             const float* __restrict__ sfLastU,
                             const unsigned short* __restrict__ h_i,
                             const float* __restrict__ emb_row,
                             unsigned short* __restrict__ embc,
                             float* __restrict__ outTail,
                             const float* __restrict__ HWrow,
                             const float* __restrict__ B2row,
                             unsigned short* __restrict__ hiddenA)
{
    int b = blockIdx.x, e = threadIdx.x;
    int wave = e >> 6, lane = e & 63;
    __shared__ float sred[4];
    float ps = (e < NSLOT) ? rowPart[(size_t)b * RPSTRIDE + e] : 0.f;
    for (int off = 32; off; off >>= 1) ps += __shfl_down(ps, off);
    if (lane == 0) sred[wave] = ps;
    __syncthreads();
    float inv = 1.f / (sred[0] + sred[1] + sred[2] + sred[3]);

    float x1 = 0.f;
#pragma unroll
    for (int z = 0; z < NSLICE; ++z)
        x1 += b2f(emb1p[(size_t)z * (Bv * Ev) + (size_t)b * Ev + e]);

    if (HWrow) {
        float v = x1 * inv + sfLastU[b] * inv * HWrow[(size_t)b * 256 + e] + B2row[e];
        hiddenA[(size_t)b * 256 + e] = f2b(v > 0.f ? v : 0.f);
    } else {
        float v = (x1 + sfLastU[b] * b2f(h_i[(size_t)b * Ev + e])) * inv;
        embc[(size_t)b * 512 + e] = f2b(v);
        float w = emb_row[e];
        embc[(size_t)b * 512 + 256 + e]    = f2b(w);
        outTail[(size_t)b * 512 + e]       = v;
        outTail[(size_t)b * 512 + 256 + e] = w;
    }
}

extern "C" void kernel_launch(void* const* d_in, const int* in_sizes, int n_in,
                              void* d_out, int out_size, void* d_ws, size_t ws_size,
                              hipStream_t stream)
{
    const int*   bodys = (const int*)d_in[0];
    const float* emb_w = (const float*)d_in[1];
    const float* w_ih  = (const float*)d_in[2];
    const float* w_hh  = (const float*)d_in[3];
    const float* b_ih  = (const float*)d_in[4];
    const float* b_hh  = (const float*)d_in[5];
    const float* fc1_w = (const float*)d_in[6];
    const float* fc1_b = (const float*)d_in[7];
    const float* fc2_w = (const float*)d_in[8];
    const float* fc2_b = (const float*)d_in[9];
    float* out = (float*)d_out;

    char* ws = (char*)d_ws;
    size_t off = 0;
    auto alloc = [&](size_t bytes) -> void* {
        void* p = ws + off;
        off += (bytes + 255) & ~(size_t)255;
        return p;
    };
    unsigned short* x       = (unsigned short*)alloc((size_t)Bv * Lv * Ev * 2);
    unsigned short* hs      = (unsigned short*)alloc((size_t)Lv * Bv * Ev * 2);
    float*          cbuf    = (float*)alloc((size_t)Bv * Ev * 4);
    float*          xg      = (float*)alloc((size_t)Bv * Lv * 1024 * 4);   // 33.5 MB
    unsigned short* embT    = (unsigned short*)alloc((size_t)Ev * PS2 * 2);
    unsigned short* sfA     = (unsigned short*)alloc((size_t)Bv * PS2 * 2);
    float*          sfLastU = (float*)alloc((size_t)Bv * 4);
    float*          rowPart = (float*)alloc((size_t)Bv * RPSTRIDE * 4);
    unsigned short* emb1p   = (unsigned short*)alloc((size_t)NSLICE * Bv * Ev * 2);
    unsigned short* embc    = (unsigned short*)alloc((size_t)Bv * 512 * 2);
    unsigned short* hiddenA = (unsigned short*)alloc((size_t)Bv * Ev * 2);
    unsigned short* w_ih_b  = (unsigned short*)alloc((size_t)1024 * Ev * 2);
    unsigned short* w_hh_b  = (unsigned short*)alloc((size_t)1024 * Ev * 2);
    float*          biasC   = (float*)alloc((size_t)1024 * 4);
    float*          B2      = (float*)alloc((size_t)7 * 256 * 4);
    unsigned short* fc1_w_b = (unsigned short*)alloc((size_t)Ev * 512 * 2);
    unsigned short* fc2_w_b = (unsigned short*)alloc((size_t)NPAD * Ev * 2);
    unsigned short* emb_w_b = (unsigned short*)alloc((size_t)NPAD * Ev * 2);
    unsigned short* EW1T    = (unsigned short*)alloc((size_t)Ev * PS2 * 2);
    float*          HW      = (float*)alloc((size_t)Lv * Bv * Ev * 4);     // 8.4 MB
    (void)ws_size; (void)in_sizes; (void)n_in; (void)out_size;

    // all input-only prep in ONE launch
    prep_k<<<7592, 256, 0, stream>>>(w_ih, w_hh, fc1_w, fc2_w, b_ih, b_hh,
                                     bodys, emb_w, fc1_b,
                                     w_ih_b, w_hh_b, fc1_w_b, fc2_w_b, biasC, x,
                                     embT, embc, sfA, B2, emb_w_b, EW1T);

    // EW1T = (emb_w @ W1a^T)^T : M=256(e) x N=10112(r), K=256; bf16 zero-invalid
    gemm_tile<<<dim3(4, 79, 1), 256, 0, stream>>>(
        fc1_w_b, 512, emb_w_b, Ev,
        nullptr,
        Ev, Ev, Rv, 3,
        nullptr, EW1T, PS2, nullptr, nullptr);

    // fc1 for i=0 (depends only on prep's embc), K=512
    gemm64<<<64, 256, 0, stream>>>(
        embc, 512, fc1_w_b, 512,
        fc1_b,
        512, 256, 1,
        nullptr, hiddenA, 256, 2,
        nullptr, 0);

    // x-gate hoist: xg = x_all(8192x256) @ w_ih^T(1024x256) -> f32
    gemm_tile<<<dim3(128, 8, 1), 256, 0, stream>>>(
        x, Ev, w_ih_b, Ev,
        nullptr,
        Ev, Ev, 1024, 0,
        xg, nullptr, 1024, nullptr, nullptr);

    // LSTM recurrence: 7 steps (t=7 is dead: body_hid[:,7] never consumed)
    for (int t = 0; t < 7; ++t) {
        gemm64<<<256, 256, 0, stream>>>(
            hs + (size_t)(t ? t - 1 : 0) * Bv * Ev, Ev, w_hh_b, Ev,
            biasC,
            (t == 0) ? 0 : Ev, 1024, 4 | (t == 0 ? 8 : 0),
            cbuf, hs + (size_t)t * Bv * Ev, 1024, 4,
            xg, t);
    }

    // HW = hs[t=1..5](5120x256) @ W1a^T(256x256) -> f32 (only t=1..5 consumed)
    gemm_tile<<<dim3(80, 2, 1), 256, 0, stream>>>(
        hs + (size_t)Bv * Ev, Ev, fc1_w_b, 512,
        nullptr,
        Ev, Ev, Ev, 0,
        HW + (size_t)Bv * Ev, nullptr, Ev, nullptr, nullptr);

    for (int i = 0; i < 7; ++i) {
        if (i > 0) {
            bool last = (i == 6);
            // X1/emb_1: sfA @ (EW1T | embT)^T -> 16 bf16 slices
            gemm_tile<<<512, 256, 0, stream>>>(
                sfA, PS2, last ? embT : EW1T, PS2,
                nullptr,
                PS2, PS2 / NSLICE, Ev, 2 | (2 << 4),
                nullptr, emb1p, Ev, nullptr, nullptr);
            finalize_emb<<<Bv, 256, 0, stream>>>(
                emb1p, rowPart, sfLastU,
                hs + (size_t)i * Bv * Ev, emb_w + (size_t)(i + 1) * Ev,
                embc, out + (size_t)Bv * NP1,
                last ? nullptr : (HW + (size_t)i * Bv * Ev),
                last ? nullptr : (B2 + (size_t)i * 256),
                hiddenA);
            if (last) {
                // fc1 for i=6 (emb_1 materialized; broadcast half via B2)
                gemm64<<<64, 256, 0, stream>>>(
                    embc, 512, fc1_w_b, 512,
                    B2 + (size_t)6 * 256,
                    256, 256, 1,
                    nullptr, hiddenA, 256, 2,
                    nullptr, 0);
            }
        }
        // fc2: prob = hidden(1024x256) @ fc2_w^T (swz=1)
        if (i < 6) {
            gemm_tile<<<1280, 256, 0, stream>>>(
                hiddenA, Ev, fc2_w_b, Ev,
                fc2_b,
                Ev, Ev, NP1, 5 | (1 << 4),
                nullptr, sfA, PS2, rowPart, sfLastU);
        } else {
            gemm_tile<<<1280, 256, 0, stream>>>(
                hiddenA, Ev, fc2_w_b, Ev,
                fc2_b,
                Ev, Ev, NP1, 0 | (1 << 4),
                out, nullptr, NP1, nullptr, nullptr);
        }
    }
}